// Round 8
// baseline (386.010 us; speedup 1.0000x reference)
//
#include <hip/hip_runtime.h>

// Problem constants
constexpr int kT = 512;     // sequence length
constexpr int kF = 64;      // input features
constexpr int kC = 256;     // f_out
constexpr int kH = 4;       // heads
constexpr int kHD = 64;     // head dim
constexpr int kBN = 128;    // B*N independent problems

typedef __attribute__((ext_vector_type(4))) float f32x4;
typedef __attribute__((ext_vector_type(8))) short s16x8;
typedef __attribute__((ext_vector_type(4))) unsigned int u32x4;

__device__ inline unsigned short f2bf(float f) {
  unsigned int u = __float_as_uint(f);
  u += 0x7fff + ((u >> 16) & 1);  // round-to-nearest-even
  return (unsigned short)(u >> 16);
}

__device__ inline float max3f(float a, float b, float c) {
  return fmaxf(fmaxf(a, b), c);   // fuses to v_max3_f32
}

__device__ inline float exp2_hw(float x) {
  float r;
  asm("v_exp_f32 %0, %1" : "=v"(r) : "v"(x));
  return r;
}

// ---------------------------------------------------------------------------
// Kernel 0: weight precompute.
// WB  [768][64]  = [Wq;Wk;Wv]^T rows c, cols f   (bf16)
// WoT [256][256] = Wo^T rows co, cols c          (bf16)
// ---------------------------------------------------------------------------
__global__ __launch_bounds__(256) void k_prep(
    const float* __restrict__ Wq, const float* __restrict__ Wk,
    const float* __restrict__ Wv, const float* __restrict__ Wo,
    unsigned short* __restrict__ WB, unsigned short* __restrict__ WoT) {
  int i = blockIdx.x * 256 + threadIdx.x;
  const int total = 768 * 64 + 256 * 256;
  for (; i < total; i += gridDim.x * 256) {
    if (i < 768 * 64) {
      int c = i >> 6, f = i & 63;
      int arr = c >> 8, cc = c & 255;
      const float* W = (arr == 0) ? Wq : (arr == 1) ? Wk : Wv;
      WB[i] = f2bf(W[f * 256 + cc]);
    } else {
      int j = i - 768 * 64;
      int co = j >> 8, c = j & 255;
      WoT[j] = f2bf(Wo[c * 256 + co]);
    }
  }
}

// ---------------------------------------------------------------------------
// Kernel 1: QKV projection. Block = (bn, 128-row t-chunk), 256 thr.
// Q pre-scaled by 0.125*log2(e) (softmax done in exp2 domain downstream).
// Q,K out: [bn][h][t][d] bf16. V out: [bn][h][d][t] via per-wave LDS bounce.
// ---------------------------------------------------------------------------
__global__ __launch_bounds__(256) void k_qkv(
    const float* __restrict__ x, const unsigned short* __restrict__ WB,
    const float* __restrict__ bq, const float* __restrict__ bk,
    const float* __restrict__ bv,
    unsigned short* __restrict__ Qw, unsigned short* __restrict__ Kw,
    unsigned short* __restrict__ Vw, int bn0) {
  // overlay: xT [128][72] u16 (18432 B) , then per-wave V bounce [16][144] u16
  __shared__ __align__(16) unsigned short shm[9216];

  const int tid = threadIdx.x;
  const int lbn = blockIdx.x >> 2;
  const int tch = blockIdx.x & 3;
  const float* xb = x + (size_t)(bn0 + lbn) * kF * kT + tch * 128;

  // stage x^T chunk as bf16 (float4 global loads)
  for (int idx = tid; idx < 2048; idx += 256) {
    int f = idx >> 5, t4 = idx & 31;
    float4 v = *(const float4*)(xb + f * kT + t4 * 4);
    shm[(t4 * 4 + 0) * 72 + f] = f2bf(v.x);
    shm[(t4 * 4 + 1) * 72 + f] = f2bf(v.y);
    shm[(t4 * 4 + 2) * 72 + f] = f2bf(v.z);
    shm[(t4 * 4 + 3) * 72 + f] = f2bf(v.w);
  }
  __syncthreads();

  const int lane = tid & 63, wid = tid >> 6;
  const int lr = lane & 15, lg = lane >> 4;

  // preload all B-frags (xT) for this wave, then free shm for bounce use
  s16x8 bfr[8][2];
#pragma unroll
  for (int tj = 0; tj < 8; ++tj)
#pragma unroll
    for (int kk = 0; kk < 2; ++kk)
      bfr[tj][kk] = *(const s16x8*)&shm[(tj * 16 + lr) * 72 + kk * 32 + lg * 8];
  __syncthreads();

  const float kQscale = 0.180336880111120426f;  // 0.125 * log2(e)

  for (int i = 0; i < 12; ++i) {
    const int ci = wid * 12 + i;
    const int c0 = ci * 16;
    s16x8 af0 = *(const s16x8*)(WB + (size_t)(c0 + lr) * 64 + lg * 8);
    s16x8 af1 = *(const s16x8*)(WB + (size_t)(c0 + lr) * 64 + 32 + lg * 8);

    f32x4 acc[8];
#pragma unroll
    for (int tj = 0; tj < 8; ++tj) {
      f32x4 a = {0.f, 0.f, 0.f, 0.f};
      a = __builtin_amdgcn_mfma_f32_16x16x32_bf16(af0, bfr[tj][0], a, 0, 0, 0);
      a = __builtin_amdgcn_mfma_f32_16x16x32_bf16(af1, bfr[tj][1], a, 0, 0, 0);
      acc[tj] = a;
    }

    const int arr = c0 >> 8;
    const int h = (c0 & 255) >> 6;
    const int dbase0 = (c0 & 63);
    const int dbase = dbase0 + lg * 4;
    const float* bsrc = (arr == 0) ? bq : (arr == 1) ? bk : bv;
    float b0 = bsrc[h * 64 + dbase + 0];
    float b1 = bsrc[h * 64 + dbase + 1];
    float b2 = bsrc[h * 64 + dbase + 2];
    float b3 = bsrc[h * 64 + dbase + 3];

    if (arr < 2) {
      const float scale = (arr == 0) ? kQscale : 1.0f;
      unsigned short* dst = ((arr == 0) ? Qw : Kw) +
                            (size_t)(lbn * kH + h) * kT * kHD;
#pragma unroll
      for (int tj = 0; tj < 8; ++tj) {
        int t = tch * 128 + tj * 16 + lr;
        float v0 = (acc[tj][0] + b0) * scale;
        float v1 = (acc[tj][1] + b1) * scale;
        float v2 = (acc[tj][2] + b2) * scale;
        float v3 = (acc[tj][3] + b3) * scale;
        unsigned long long pk =
            (unsigned long long)f2bf(v0) |
            ((unsigned long long)f2bf(v1) << 16) |
            ((unsigned long long)f2bf(v2) << 32) |
            ((unsigned long long)f2bf(v3) << 48);
        *(unsigned long long*)(dst + (size_t)t * kHD + dbase) = pk;
      }
    } else {
      // V^T tile via per-wave LDS bounce: [16 d][128 t] -> coalesced stores
      unsigned short* buf = shm + wid * (16 * 144);
#pragma unroll
      for (int tj = 0; tj < 8; ++tj) {
        buf[(lg * 4 + 0) * 144 + tj * 16 + lr] = f2bf(acc[tj][0] + b0);
        buf[(lg * 4 + 1) * 144 + tj * 16 + lr] = f2bf(acc[tj][1] + b1);
        buf[(lg * 4 + 2) * 144 + tj * 16 + lr] = f2bf(acc[tj][2] + b2);
        buf[(lg * 4 + 3) * 144 + tj * 16 + lr] = f2bf(acc[tj][3] + b3);
      }
      asm volatile("s_waitcnt lgkmcnt(0)" ::: "memory");
      unsigned short* dst = Vw + (size_t)(lbn * kH + h) * kHD * kT;
      const int row = lane >> 2, cc = lane & 3;
#pragma unroll
      for (int q4 = 0; q4 < 4; ++q4) {
        uint4 vv = *(const uint4*)&buf[row * 144 + (q4 * 4 + cc) * 8];
        *(uint4*)(dst + (size_t)(dbase0 + row) * kT + tch * 128 +
                  (q4 * 4 + cc) * 8) = vv;
      }
    }
  }
}

// ---------------------------------------------------------------------------
// Kernel 2: flash attention per (bn, head). 1024 threads = 16 waves, each
// owning 32 q-rows (2 x 16-tiles). K-frags read directly from global (L1-
// resident, 16x intra-block reuse) in parallel with V's LDS port. Only V^T
// (kappa-permuted, swizzled) lives in LDS (64 KB) -> 2 blocks/CU,
// 32 waves/CU = 8 waves/SIMD for latency hiding. Softmax: exp2-domain
// defer-max (THR=8), bounded for ANY score magnitude; common path has no
// cross-lane ops and no barriers.
// ---------------------------------------------------------------------------
__global__ __launch_bounds__(1024, 8) void k_attn(
    const unsigned short* __restrict__ Qw, const unsigned short* __restrict__ Kw,
    const unsigned short* __restrict__ Vw, unsigned short* __restrict__ Aw) {
  __shared__ __align__(16) unsigned char VtB[64 * 1024];   // [d][pos] swizzled

  const int tid = threadIdx.x;
  const int lbn = blockIdx.x >> 2;
  const int h = blockIdx.x & 3;
  const size_t hb = (size_t)(lbn * kH + h) * kT * kHD;

  // --- stage V^T with kappa pre-permutation (8-byte granularity) ---
  // position p = 8h+u (within 32-block) holds key 16*(u>>2) + 4*h + (u&3)
  const unsigned short* Vs = Vw + hb;
#pragma unroll
  for (int i = 0; i < 8; ++i) {
    int gi = tid + i * 1024;            // 8-byte group index, [0, 8192)
    int d = gi >> 7, gr = gi & 127;
    int b32 = gr >> 3, g2 = gr & 7;
    int hh = g2 >> 1, e = g2 & 1;
    uint2 v = *(const uint2*)(Vs + d * 512 + b32 * 32 + e * 16 + hh * 4);
    *(uint2*)(VtB + ((d * 1024 + gr * 8) ^ ((d & 7) << 4))) = v;
  }
  __syncthreads();

  const int lane = tid & 63, wid = tid >> 6;
  const int lr = lane & 15, lg = lane >> 4;
  const int swz = (lr & 7) << 4;
  const unsigned short* Qb = Qw + hb;
  unsigned short* Ab = Aw + (size_t)lbn * kT * kC + h * kHD;

  const int qbase = wid * 32;
  s16x8 qf[2][2];
#pragma unroll
  for (int qt = 0; qt < 2; ++qt) {
    qf[qt][0] = *(const s16x8*)(Qb + (size_t)(qbase + qt * 16 + lr) * kHD + lg * 8);
    qf[qt][1] = *(const s16x8*)(Qb + (size_t)(qbase + qt * 16 + lr) * kHD + 32 + lg * 8);
  }

  f32x4 o[2][4] = {{{0,0,0,0},{0,0,0,0},{0,0,0,0},{0,0,0,0}},
                   {{0,0,0,0},{0,0,0,0},{0,0,0,0},{0,0,0,0}}};
  float l[2] = {0.f, 0.f};
  float m[2] = {-3e38f, -3e38f};

  // K global base: row (k) = kb + 16s + lr, d-frag at lg*8 (+32 for hi half)
  const unsigned short* kg = Kw + hb + lr * kHD + lg * 8;
  // V LDS base pointers (advanced 128 B per kc)
  const unsigned char* vp0 = VtB + lr * 1024 + ((lg * 16) ^ swz);
  const unsigned char* vp1 = VtB + lr * 1024 + (((lg * 16) ^ 64) ^ swz);

  for (int kc = 0; kc < 8; ++kc) {
    const unsigned short* kgc = kg + kc * 64 * kHD;
    s16x8 kf0[4], kf1[4];
#pragma unroll
    for (int s = 0; s < 4; ++s) {
      kf0[s] = *(const s16x8*)(kgc + s * 16 * kHD);
      kf1[s] = *(const s16x8*)(kgc + s * 16 * kHD + 32);
    }

    // sa[qt][s][r] = S2[k = kb+16s+4lg+r][q = qbase+16qt+lr]  (log2 domain)
    f32x4 sa[2][4];
#pragma unroll
    for (int qt = 0; qt < 2; ++qt)
#pragma unroll
      for (int s = 0; s < 4; ++s) {
        f32x4 z = {0.f, 0.f, 0.f, 0.f};
        z = __builtin_amdgcn_mfma_f32_16x16x32_bf16(kf0[s], qf[qt][0], z, 0, 0, 0);
        z = __builtin_amdgcn_mfma_f32_16x16x32_bf16(kf1[s], qf[qt][1], z, 0, 0, 0);
        sa[qt][s] = z;
      }

    // defer-max softmax (THR=8 in log2 domain); per-lane partial l
    s16x8 pa[2][2];
#pragma unroll
    for (int qt = 0; qt < 2; ++qt) {
      float g0 = max3f(sa[qt][0][0], sa[qt][0][1], sa[qt][0][2]);
      float g1 = max3f(sa[qt][0][3], sa[qt][1][0], sa[qt][1][1]);
      float g2 = max3f(sa[qt][1][2], sa[qt][1][3], sa[qt][2][0]);
      float g3 = max3f(sa[qt][2][1], sa[qt][2][2], sa[qt][2][3]);
      float g4 = max3f(sa[qt][3][0], sa[qt][3][1], sa[qt][3][2]);
      float tm = fmaxf(max3f(g0, g1, g2), max3f(g3, g4, sa[qt][3][3]));
      if (__any(tm > m[qt] + 8.0f)) {
        tm = fmaxf(tm, __shfl_xor(tm, 16));
        tm = fmaxf(tm, __shfl_xor(tm, 32));
        float mn = fmaxf(m[qt], tm);
        float al = exp2_hw(m[qt] - mn);
        m[qt] = mn;
        l[qt] *= al;
        float aq0 = __shfl(al, (lane & 48) | (lg * 4 + 0));
        float aq1 = __shfl(al, (lane & 48) | (lg * 4 + 1));
        float aq2 = __shfl(al, (lane & 48) | (lg * 4 + 2));
        float aq3 = __shfl(al, (lane & 48) | (lg * 4 + 3));
#pragma unroll
        for (int dt = 0; dt < 4; ++dt) {
          o[qt][dt][0] *= aq0; o[qt][dt][1] *= aq1;
          o[qt][dt][2] *= aq2; o[qt][dt][3] *= aq3;
        }
      }
      unsigned int w[8];
#pragma unroll
      for (int s = 0; s < 4; ++s) {
        float e0 = exp2_hw(sa[qt][s][0] - m[qt]);
        float e1 = exp2_hw(sa[qt][s][1] - m[qt]);
        float e2 = exp2_hw(sa[qt][s][2] - m[qt]);
        float e3 = exp2_hw(sa[qt][s][3] - m[qt]);
        l[qt] += (e0 + e1) + (e2 + e3);
        asm("v_cvt_pk_bf16_f32 %0, %1, %2" : "=v"(w[2*s])   : "v"(e0), "v"(e1));
        asm("v_cvt_pk_bf16_f32 %0, %1, %2" : "=v"(w[2*s+1]) : "v"(e2), "v"(e3));
      }
      pa[qt][0] = __builtin_bit_cast(s16x8, (u32x4){w[0], w[1], w[2], w[3]});
      pa[qt][1] = __builtin_bit_cast(s16x8, (u32x4){w[4], w[5], w[6], w[7]});
    }

    // PV: each vb frag feeds both q-tiles
#pragma unroll
    for (int dt = 0; dt < 4; ++dt) {
      s16x8 vb = *(const s16x8*)(vp0 + dt * 16384);
      o[0][dt] = __builtin_amdgcn_mfma_f32_16x16x32_bf16(pa[0][0], vb,
                                                         o[0][dt], 0, 0, 0);
      o[1][dt] = __builtin_amdgcn_mfma_f32_16x16x32_bf16(pa[1][0], vb,
                                                         o[1][dt], 0, 0, 0);
    }
#pragma unroll
    for (int dt = 0; dt < 4; ++dt) {
      s16x8 vb = *(const s16x8*)(vp1 + dt * 16384);
      o[0][dt] = __builtin_amdgcn_mfma_f32_16x16x32_bf16(pa[0][1], vb,
                                                         o[0][dt], 0, 0, 0);
      o[1][dt] = __builtin_amdgcn_mfma_f32_16x16x32_bf16(pa[1][1], vb,
                                                         o[1][dt], 0, 0, 0);
    }
    vp0 += 128;
    vp1 += 128;
  }

  // epilogue: cross-lane l sum, normalize, write
#pragma unroll
  for (int qt = 0; qt < 2; ++qt) {
    float lq = l[qt];
    float l2 = lq + __shfl_xor(lq, 16);
    float lr4 = l2 + __shfl_xor(l2, 32);
    float li0 = 1.0f / __shfl(lr4, (lane & 48) | (lg * 4 + 0));
    float li1 = 1.0f / __shfl(lr4, (lane & 48) | (lg * 4 + 1));
    float li2 = 1.0f / __shfl(lr4, (lane & 48) | (lg * 4 + 2));
    float li3 = 1.0f / __shfl(lr4, (lane & 48) | (lg * 4 + 3));
    const int qb = qbase + qt * 16;
#pragma unroll
    for (int r = 0; r < 4; ++r) {
      float li = (r == 0) ? li0 : (r == 1) ? li1 : (r == 2) ? li2 : li3;
      unsigned short* orow = Ab + (size_t)(qb + lg * 4 + r) * kC;
#pragma unroll
      for (int dt = 0; dt < 4; ++dt)
        orow[dt * 16 + lr] = f2bf(o[qt][dt][r] * li);
    }
  }
}

// ---------------------------------------------------------------------------
// Kernel 3: output projection + bias + transpose. Block = (bn, 128-t chunk),
// 512 thr = 8 waves (2 t-halves x 4 co-quads). A staged ONCE in swizzled LDS.
// out[bn][co][t] fp32.
// ---------------------------------------------------------------------------
__global__ __launch_bounds__(512) void k_proj(
    const unsigned short* __restrict__ Aw, const unsigned short* __restrict__ WoT,
    const float* __restrict__ bo, float* __restrict__ out, int bn0) {
  __shared__ __align__(16) unsigned char Al[128 * 512];  // [t][c] swizzled, 64KB

  const int tid = threadIdx.x;
  const int lbn = blockIdx.x >> 2;
  const int tch = blockIdx.x & 3;
  const int t0 = tch * 128;

  const uint4* Asrc = (const uint4*)(Aw + ((size_t)lbn * kT + t0) * kC);
#pragma unroll
  for (int i = 0; i < 8; ++i) {
    int idx = tid + i * 512;
    int trow = idx >> 5, cc = idx & 31;
    *(uint4*)(Al + ((trow * 512 + cc * 16) ^ ((trow & 7) << 4))) = Asrc[idx];
  }
  __syncthreads();

  const int lane = tid & 63, wid = tid >> 6;
  const int lr = lane & 15, lg = lane >> 4;
  const int swz = (lr & 7) << 4;
  const int tb = (wid >> 2) * 64;
  const int cob = (wid & 3) * 64;

  float* ob = out + (size_t)(bn0 + lbn) * kC * kT;

  for (int ci = 0; ci < 4; ++ci) {
    const int co0 = cob + ci * 16;
    s16x8 af[8];
#pragma unroll
    for (int kc = 0; kc < 8; ++kc)
      af[kc] = *(const s16x8*)(WoT + (size_t)(co0 + lr) * 256 + kc * 32 + lg * 8);
    float b4[4];
#pragma unroll
    for (int r = 0; r < 4; ++r) b4[r] = bo[co0 + lg * 4 + r];

#pragma unroll
    for (int tj = 0; tj < 4; ++tj) {
      const unsigned char* ap = Al + (tb + tj * 16 + lr) * 512;
      f32x4 acc = {0.f, 0.f, 0.f, 0.f};
#pragma unroll
      for (int kc = 0; kc < 8; ++kc) {
        s16x8 bfr = *(const s16x8*)(ap + ((kc * 64 + lg * 16) ^ swz));
        acc = __builtin_amdgcn_mfma_f32_16x16x32_bf16(af[kc], bfr, acc, 0, 0, 0);
      }
      int t = t0 + tb + tj * 16 + lr;
#pragma unroll
      for (int r = 0; r < 4; ++r)
        ob[(size_t)(co0 + lg * 4 + r) * kT + t] = acc[r] + b4[r];
    }
  }
}

// ---------------------------------------------------------------------------
extern "C" void kernel_launch(void* const* d_in, const int* in_sizes, int n_in,
                              void* d_out, int out_size, void* d_ws, size_t ws_size,
                              hipStream_t stream) {
  const float* x  = (const float*)d_in[0];
  const float* Wq = (const float*)d_in[1];
  const float* bq = (const float*)d_in[2];
  const float* Wk = (const float*)d_in[3];
  const float* bk = (const float*)d_in[4];
  const float* Wv = (const float*)d_in[5];
  const float* bv = (const float*)d_in[6];
  const float* Wo = (const float*)d_in[7];
  const float* bo = (const float*)d_in[8];
  float* out = (float*)d_out;

  const size_t wElems = 768 * 64 + 256 * 256;
  const size_t perbn = (size_t)4 * kT * kC * 2;    // 1 MB
  if (ws_size < wElems * 2 + perbn) return;
  int cap = (int)((ws_size - wElems * 2) / perbn);
  if (cap > kBN) cap = kBN;

  unsigned short* WB  = (unsigned short*)d_ws;
  unsigned short* WoT = WB + 768 * 64;
  unsigned short* Q = WB + wElems;
  unsigned short* K = Q + (size_t)cap * kT * kC;
  unsigned short* V = K + (size_t)cap * kT * kC;
  unsigned short* A = V + (size_t)cap * kT * kC;

  k_prep<<<dim3(448), dim3(256), 0, stream>>>(Wq, Wk, Wv, Wo, WB, WoT);

  for (int s = 0; s < kBN; s += cap) {
    int nb = (kBN - s < cap) ? (kBN - s) : cap;
    k_qkv<<<dim3(nb * 4), dim3(256), 0, stream>>>(x, WB, bq, bk, bv,
                                                  Q, K, V, s);
    k_attn<<<dim3(nb * 4), dim3(1024), 0, stream>>>(Q, K, V, A);
    k_proj<<<dim3(nb * 4), dim3(512), 0, stream>>>(A, WoT, bo, out, s);
  }
}

// Round 9
// 126.459 us; speedup vs baseline: 3.0525x; 3.0525x over previous
//
#include <hip/hip_runtime.h>

// Problem constants
constexpr int kT = 512;     // sequence length
constexpr int kF = 64;      // input features
constexpr int kC = 256;     // f_out
constexpr int kH = 4;       // heads
constexpr int kHD = 64;     // head dim
constexpr int kBN = 128;    // B*N independent problems

typedef __attribute__((ext_vector_type(4))) float f32x4;
typedef __attribute__((ext_vector_type(8))) short s16x8;
typedef __attribute__((ext_vector_type(4))) unsigned int u32x4;

__device__ inline unsigned short f2bf(float f) {
  unsigned int u = __float_as_uint(f);
  u += 0x7fff + ((u >> 16) & 1);  // round-to-nearest-even
  return (unsigned short)(u >> 16);
}

__device__ inline float max3f(float a, float b, float c) {
  return fmaxf(fmaxf(a, b), c);   // fuses to v_max3_f32
}

__device__ inline float exp2_hw(float x) {
  float r;
  asm("v_exp_f32 %0, %1" : "=v"(r) : "v"(x));
  return r;
}

// ---------------------------------------------------------------------------
// Kernel 0: weight precompute.
// WB  [768][64]  = [Wq;Wk;Wv]^T rows c, cols f   (bf16)
// WoT [256][256] = Wo^T rows co, cols c          (bf16)
// ---------------------------------------------------------------------------
__global__ __launch_bounds__(256) void k_prep(
    const float* __restrict__ Wq, const float* __restrict__ Wk,
    const float* __restrict__ Wv, const float* __restrict__ Wo,
    unsigned short* __restrict__ WB, unsigned short* __restrict__ WoT) {
  int i = blockIdx.x * 256 + threadIdx.x;
  const int total = 768 * 64 + 256 * 256;
  for (; i < total; i += gridDim.x * 256) {
    if (i < 768 * 64) {
      int c = i >> 6, f = i & 63;
      int arr = c >> 8, cc = c & 255;
      const float* W = (arr == 0) ? Wq : (arr == 1) ? Wk : Wv;
      WB[i] = f2bf(W[f * 256 + cc]);
    } else {
      int j = i - 768 * 64;
      int co = j >> 8, c = j & 255;
      WoT[j] = f2bf(Wo[c * 256 + co]);
    }
  }
}

// ---------------------------------------------------------------------------
// Kernel 1: FUSED QKV + flash attention per (bn, head). 1024 thr = 16 waves.
// Prologue (per 128-t chunk): stage x^T chunk as bf16 -> all waves compute
// K,V tiles via MFMA, writing K into swizzled Kl [t][d] and V into
// kappa-permuted swizzled VtB [d][pos] (the exact layouts the r5 attention
// loop consumes); the 4 waves owning this chunk's q-rows also compute Q,
// bounce it through the x-chunk LDS area, and load their qf fragments.
// Main loop: r5's proven attention (defer-max exp2 softmax, in-register P,
// LDS K + V, no barriers). LDS 146 KB -> 1 block/CU, 16 waves (4/SIMD).
// ---------------------------------------------------------------------------
__global__ __launch_bounds__(1024, 4) void k_fattn(
    const float* __restrict__ x, const unsigned short* __restrict__ WB,
    const float* __restrict__ bq, const float* __restrict__ bk,
    const float* __restrict__ bv, unsigned short* __restrict__ Aw) {
  __shared__ __align__(16) unsigned char smem[149504];
  unsigned char* Kl = smem;                              // 64 KB  [512][128B] swz
  unsigned char* VtB = smem + 65536;                     // 64 KB  [64][1024B] swz
  unsigned short* xC = (unsigned short*)(smem + 131072); // 18 KB  [128][72] u16

  const int tid = threadIdx.x;
  const int lbn = blockIdx.x >> 2;
  const int h = blockIdx.x & 3;
  const int lane = tid & 63, wid = tid >> 6;
  const int lr = lane & 15, lg = lane >> 4;
  const int swz = (lr & 7) << 4;

  const float kQscale = 0.180336880111120426f;  // 0.125 * log2(e)
  const unsigned short* WBq = WB + (size_t)(h * 64) * 64;
  const unsigned short* WBk = WB + (size_t)(256 + h * 64) * 64;
  const unsigned short* WBv = WB + (size_t)(512 + h * 64) * 64;

  s16x8 qf[2][2];

  // ============ QKV build ============
  for (int tch = 0; tch < 4; ++tch) {
    __syncthreads();  // prior-iteration qf reads done before xC overwrite
    const float* xb = x + (size_t)lbn * kF * kT + tch * 128;
#pragma unroll
    for (int it = 0; it < 2; ++it) {
      int idx = tid + it * 1024;
      int f = idx >> 5, t4 = idx & 31;
      float4 v = *(const float4*)(xb + f * kT + t4 * 4);
      xC[(t4 * 4 + 0) * 72 + f] = f2bf(v.x);
      xC[(t4 * 4 + 1) * 72 + f] = f2bf(v.y);
      xC[(t4 * 4 + 2) * 72 + f] = f2bf(v.z);
      xC[(t4 * 4 + 3) * 72 + f] = f2bf(v.w);
    }
    __syncthreads();  // xC ready

    // K/V tiles: tau = wid*4 + j ; tau<32 -> K(ct=tau>>3,tt=tau&7), else V
#pragma unroll
    for (int j = 0; j < 4; ++j) {
      const int tau = wid * 4 + j;
      const int isV = tau >> 5;
      const int tl = tau & 31;
      const int ct = tl >> 3, tt = tl & 7;
      const unsigned short* Wsrc = isV ? WBv : WBk;
      s16x8 af0 = *(const s16x8*)(Wsrc + (ct * 16 + lr) * 64 + lg * 8);
      s16x8 af1 = *(const s16x8*)(Wsrc + (ct * 16 + lr) * 64 + 32 + lg * 8);
      s16x8 bf0 = *(const s16x8*)&xC[(tt * 16 + lr) * 72 + lg * 8];
      s16x8 bf1 = *(const s16x8*)&xC[(tt * 16 + lr) * 72 + 32 + lg * 8];
      f32x4 a = {0.f, 0.f, 0.f, 0.f};
      a = __builtin_amdgcn_mfma_f32_16x16x32_bf16(af0, bf0, a, 0, 0, 0);
      a = __builtin_amdgcn_mfma_f32_16x16x32_bf16(af1, bf1, a, 0, 0, 0);
      const float* bsrc = isV ? bv : bk;
      const int dbase = ct * 16 + lg * 4;
      const int t = tch * 128 + tt * 16 + lr;
      float v0 = a[0] + bsrc[h * 64 + dbase + 0];
      float v1 = a[1] + bsrc[h * 64 + dbase + 1];
      float v2 = a[2] + bsrc[h * 64 + dbase + 2];
      float v3 = a[3] + bsrc[h * 64 + dbase + 3];
      if (!isV) {
        unsigned long long pk =
            (unsigned long long)f2bf(v0) |
            ((unsigned long long)f2bf(v1) << 16) |
            ((unsigned long long)f2bf(v2) << 32) |
            ((unsigned long long)f2bf(v3) << 48);
        *(unsigned long long*)(Kl + ((t * 128 + dbase * 2) ^ ((t & 7) << 4))) = pk;
      } else {
        // kappa position: t = {b32, e, hh, j2} -> pos = {b32, hh, e, j2}
        const int pos = ((t >> 5) << 5) | (((t >> 2) & 3) << 3) |
                        (((t >> 4) & 1) << 2) | (t & 3);
        const unsigned short pv[4] = {f2bf(v0), f2bf(v1), f2bf(v2), f2bf(v3)};
#pragma unroll
        for (int r = 0; r < 4; ++r) {
          const int d = dbase + r;
          *(unsigned short*)(VtB + ((d * 1024 + pos * 2) ^ ((d & 7) << 4))) = pv[r];
        }
      }
    }

    // Q tiles: the 4 waves owning this chunk's q-rows
    const bool qown = ((wid >> 2) == tch);
    f32x4 qa[2][4];
    if (qown) {
#pragma unroll
      for (int qt = 0; qt < 2; ++qt) {
        const int ttq = (wid & 3) * 2 + qt;
#pragma unroll
        for (int ct = 0; ct < 4; ++ct) {
          s16x8 af0 = *(const s16x8*)(WBq + (ct * 16 + lr) * 64 + lg * 8);
          s16x8 af1 = *(const s16x8*)(WBq + (ct * 16 + lr) * 64 + 32 + lg * 8);
          s16x8 bf0 = *(const s16x8*)&xC[(ttq * 16 + lr) * 72 + lg * 8];
          s16x8 bf1 = *(const s16x8*)&xC[(ttq * 16 + lr) * 72 + 32 + lg * 8];
          f32x4 a = {0.f, 0.f, 0.f, 0.f};
          a = __builtin_amdgcn_mfma_f32_16x16x32_bf16(af0, bf0, a, 0, 0, 0);
          a = __builtin_amdgcn_mfma_f32_16x16x32_bf16(af1, bf1, a, 0, 0, 0);
          qa[qt][ct] = a;
        }
      }
    }
    __syncthreads();  // all xC reads done; safe to overwrite with Q bounce
    if (qown) {
#pragma unroll
      for (int qt = 0; qt < 2; ++qt) {
        const int qrow = (wid & 3) * 32 + qt * 16 + lr;
#pragma unroll
        for (int ct = 0; ct < 4; ++ct) {
          f32x4 a = qa[qt][ct];
          const int dbase = ct * 16 + lg * 4;
          float q0 = (a[0] + bq[h * 64 + dbase + 0]) * kQscale;
          float q1 = (a[1] + bq[h * 64 + dbase + 1]) * kQscale;
          float q2 = (a[2] + bq[h * 64 + dbase + 2]) * kQscale;
          float q3 = (a[3] + bq[h * 64 + dbase + 3]) * kQscale;
          unsigned long long pk =
              (unsigned long long)f2bf(q0) |
              ((unsigned long long)f2bf(q1) << 16) |
              ((unsigned long long)f2bf(q2) << 32) |
              ((unsigned long long)f2bf(q3) << 48);
          *(unsigned long long*)&xC[qrow * 72 + dbase] = pk;
        }
      }
    }
    __syncthreads();  // bounce visible
    if (qown) {
#pragma unroll
      for (int qt = 0; qt < 2; ++qt) {
        const int qrow = (wid & 3) * 32 + qt * 16 + lr;
        qf[qt][0] = *(const s16x8*)&xC[qrow * 72 + lg * 8];
        qf[qt][1] = *(const s16x8*)&xC[qrow * 72 + 32 + lg * 8];
      }
    }
  }
  __syncthreads();  // Kl/VtB complete

  // ============ attention (r5-proven) ============
  unsigned short* Ab = Aw + (size_t)lbn * kT * kC + h * kHD;
  const int qbase = wid * 32;

  f32x4 o0[4] = {{0,0,0,0},{0,0,0,0},{0,0,0,0},{0,0,0,0}};
  f32x4 o1[4] = {{0,0,0,0},{0,0,0,0},{0,0,0,0},{0,0,0,0}};
  float m0 = -3e38f, m1 = -3e38f, l0 = 0.f, l1 = 0.f;

  const int koff = (lg * 16) ^ swz;
  const unsigned char* kp0 = Kl + lr * 128 + koff;
  const unsigned char* kp1 = Kl + lr * 128 + (koff ^ 64);
  const unsigned char* vp0 = VtB + lr * 1024 + ((lg * 16) ^ swz);
  const unsigned char* vp1 = VtB + lr * 1024 + (((lg * 16) ^ 64) ^ swz);

  unsigned int w0[8], w1[8];

#define SOFTMAX_QT(sa, m, l, o, w)                                            \
  {                                                                           \
    float g0 = max3f(sa[0][0], sa[0][1], sa[0][2]);                           \
    float g1 = max3f(sa[0][3], sa[1][0], sa[1][1]);                           \
    float g2 = max3f(sa[1][2], sa[1][3], sa[2][0]);                           \
    float g3 = max3f(sa[2][1], sa[2][2], sa[2][3]);                           \
    float g4 = max3f(sa[3][0], sa[3][1], sa[3][2]);                           \
    float tm = fmaxf(max3f(g0, g1, g2), max3f(g3, g4, sa[3][3]));             \
    if (__any(tm > m + 8.0f)) {                                               \
      tm = fmaxf(tm, __shfl_xor(tm, 16));                                     \
      tm = fmaxf(tm, __shfl_xor(tm, 32));                                     \
      float mn = fmaxf(m, tm);                                                \
      float al = exp2_hw(m - mn);                                             \
      m = mn;                                                                 \
      l *= al;                                                                \
      float aq0 = __shfl(al, (lane & 48) | (lg * 4 + 0));                     \
      float aq1 = __shfl(al, (lane & 48) | (lg * 4 + 1));                     \
      float aq2 = __shfl(al, (lane & 48) | (lg * 4 + 2));                     \
      float aq3 = __shfl(al, (lane & 48) | (lg * 4 + 3));                     \
      _Pragma("unroll")                                                       \
      for (int dt = 0; dt < 4; ++dt) {                                        \
        o[dt][0] *= aq0; o[dt][1] *= aq1;                                     \
        o[dt][2] *= aq2; o[dt][3] *= aq3;                                     \
      }                                                                       \
    }                                                                         \
    _Pragma("unroll")                                                         \
    for (int s = 0; s < 4; ++s) {                                             \
      float e0 = exp2_hw(sa[s][0] - m);                                       \
      float e1 = exp2_hw(sa[s][1] - m);                                       \
      float e2 = exp2_hw(sa[s][2] - m);                                       \
      float e3 = exp2_hw(sa[s][3] - m);                                       \
      l += (e0 + e1) + (e2 + e3);                                             \
      asm("v_cvt_pk_bf16_f32 %0, %1, %2" : "=v"(w[2*s]) : "v"(e0), "v"(e1));  \
      asm("v_cvt_pk_bf16_f32 %0, %1, %2" : "=v"(w[2*s+1]) : "v"(e2), "v"(e3));\
    }                                                                         \
  }

  for (int kc = 0; kc < 8; ++kc) {
    f32x4 sa0[4], sa1[4];
#pragma unroll
    for (int s = 0; s < 4; ++s) {
      s16x8 kf0 = *(const s16x8*)(kp0 + s * 2048);
      s16x8 kf1 = *(const s16x8*)(kp1 + s * 2048);
      f32x4 z0 = {0.f, 0.f, 0.f, 0.f};
      z0 = __builtin_amdgcn_mfma_f32_16x16x32_bf16(kf0, qf[0][0], z0, 0, 0, 0);
      z0 = __builtin_amdgcn_mfma_f32_16x16x32_bf16(kf1, qf[0][1], z0, 0, 0, 0);
      sa0[s] = z0;
      f32x4 z1 = {0.f, 0.f, 0.f, 0.f};
      z1 = __builtin_amdgcn_mfma_f32_16x16x32_bf16(kf0, qf[1][0], z1, 0, 0, 0);
      z1 = __builtin_amdgcn_mfma_f32_16x16x32_bf16(kf1, qf[1][1], z1, 0, 0, 0);
      sa1[s] = z1;
    }
    kp0 += 8192;
    kp1 += 8192;

    SOFTMAX_QT(sa0, m0, l0, o0, w0)
    SOFTMAX_QT(sa1, m1, l1, o1, w1)

    s16x8 pa00 = __builtin_bit_cast(s16x8, (u32x4){w0[0], w0[1], w0[2], w0[3]});
    s16x8 pa01 = __builtin_bit_cast(s16x8, (u32x4){w0[4], w0[5], w0[6], w0[7]});
    s16x8 pa10 = __builtin_bit_cast(s16x8, (u32x4){w1[0], w1[1], w1[2], w1[3]});
    s16x8 pa11 = __builtin_bit_cast(s16x8, (u32x4){w1[4], w1[5], w1[6], w1[7]});

#pragma unroll
    for (int dt = 0; dt < 4; ++dt) {
      s16x8 vb = *(const s16x8*)(vp0 + dt * 16384);
      o0[dt] = __builtin_amdgcn_mfma_f32_16x16x32_bf16(pa00, vb, o0[dt], 0, 0, 0);
      o1[dt] = __builtin_amdgcn_mfma_f32_16x16x32_bf16(pa10, vb, o1[dt], 0, 0, 0);
    }
#pragma unroll
    for (int dt = 0; dt < 4; ++dt) {
      s16x8 vb = *(const s16x8*)(vp1 + dt * 16384);
      o0[dt] = __builtin_amdgcn_mfma_f32_16x16x32_bf16(pa01, vb, o0[dt], 0, 0, 0);
      o1[dt] = __builtin_amdgcn_mfma_f32_16x16x32_bf16(pa11, vb, o1[dt], 0, 0, 0);
    }
    vp0 += 128;
    vp1 += 128;
  }
#undef SOFTMAX_QT

  // epilogue: cross-lane l sum, normalize, write
#pragma unroll
  for (int qt = 0; qt < 2; ++qt) {
    float l = (qt == 0) ? l0 : l1;
    f32x4* o = (qt == 0) ? o0 : o1;
    float l2 = l + __shfl_xor(l, 16);
    float lr4 = l2 + __shfl_xor(l2, 32);
    float li0 = 1.0f / __shfl(lr4, (lane & 48) | (lg * 4 + 0));
    float li1 = 1.0f / __shfl(lr4, (lane & 48) | (lg * 4 + 1));
    float li2 = 1.0f / __shfl(lr4, (lane & 48) | (lg * 4 + 2));
    float li3 = 1.0f / __shfl(lr4, (lane & 48) | (lg * 4 + 3));
    const int qb = qbase + qt * 16;
#pragma unroll
    for (int r = 0; r < 4; ++r) {
      float li = (r == 0) ? li0 : (r == 1) ? li1 : (r == 2) ? li2 : li3;
      unsigned short* orow = Ab + (size_t)(qb + lg * 4 + r) * kC;
#pragma unroll
      for (int dt = 0; dt < 4; ++dt)
        orow[dt * 16 + lr] = f2bf(o[dt][r] * li);
    }
  }
}

// ---------------------------------------------------------------------------
// Kernel 3: output projection + bias + transpose. Block = (bn, 128-t chunk),
// 512 thr = 8 waves (2 t-halves x 4 co-quads). A staged ONCE in swizzled LDS.
// out[bn][co][t] fp32.
// ---------------------------------------------------------------------------
__global__ __launch_bounds__(512) void k_proj(
    const unsigned short* __restrict__ Aw, const unsigned short* __restrict__ WoT,
    const float* __restrict__ bo, float* __restrict__ out) {
  __shared__ __align__(16) unsigned char Al[128 * 512];  // [t][c] swizzled, 64KB

  const int tid = threadIdx.x;
  const int lbn = blockIdx.x >> 2;
  const int tch = blockIdx.x & 3;
  const int t0 = tch * 128;

  const uint4* Asrc = (const uint4*)(Aw + ((size_t)lbn * kT + t0) * kC);
#pragma unroll
  for (int i = 0; i < 8; ++i) {
    int idx = tid + i * 512;
    int trow = idx >> 5, cc = idx & 31;
    *(uint4*)(Al + ((trow * 512 + cc * 16) ^ ((trow & 7) << 4))) = Asrc[idx];
  }
  __syncthreads();

  const int lane = tid & 63, wid = tid >> 6;
  const int lr = lane & 15, lg = lane >> 4;
  const int swz = (lr & 7) << 4;
  const int tb = (wid >> 2) * 64;
  const int cob = (wid & 3) * 64;

  float* ob = out + (size_t)lbn * kC * kT;

  for (int ci = 0; ci < 4; ++ci) {
    const int co0 = cob + ci * 16;
    s16x8 af[8];
#pragma unroll
    for (int kc = 0; kc < 8; ++kc)
      af[kc] = *(const s16x8*)(WoT + (size_t)(co0 + lr) * 256 + kc * 32 + lg * 8);
    float b4[4];
#pragma unroll
    for (int r = 0; r < 4; ++r) b4[r] = bo[co0 + lg * 4 + r];

#pragma unroll
    for (int tj = 0; tj < 4; ++tj) {
      const unsigned char* ap = Al + (tb + tj * 16 + lr) * 512;
      f32x4 acc = {0.f, 0.f, 0.f, 0.f};
#pragma unroll
      for (int kc = 0; kc < 8; ++kc) {
        s16x8 bfr = *(const s16x8*)(ap + ((kc * 64 + lg * 16) ^ swz));
        acc = __builtin_amdgcn_mfma_f32_16x16x32_bf16(af[kc], bfr, acc, 0, 0, 0);
      }
      int t = t0 + tb + tj * 16 + lr;
#pragma unroll
      for (int r = 0; r < 4; ++r)
        ob[(size_t)(co0 + lg * 4 + r) * kT + t] = acc[r] + b4[r];
    }
  }
}

// ---------------------------------------------------------------------------
extern "C" void kernel_launch(void* const* d_in, const int* in_sizes, int n_in,
                              void* d_out, int out_size, void* d_ws, size_t ws_size,
                              hipStream_t stream) {
  const float* x  = (const float*)d_in[0];
  const float* Wq = (const float*)d_in[1];
  const float* bq = (const float*)d_in[2];
  const float* Wk = (const float*)d_in[3];
  const float* bk = (const float*)d_in[4];
  const float* Wv = (const float*)d_in[5];
  const float* bv = (const float*)d_in[6];
  const float* Wo = (const float*)d_in[7];
  const float* bo = (const float*)d_in[8];
  float* out = (float*)d_out;

  // ws layout: WB bf16 [768*64] | WoT bf16 [256*256] | A bf16 [128*512*256]
  const size_t wElems = 768 * 64 + 256 * 256;             // 229376 B
  const size_t aBytes = (size_t)kBN * kT * kC * 2;        // 32 MB
  if (ws_size < wElems * 2 + aBytes) return;

  unsigned short* WB  = (unsigned short*)d_ws;
  unsigned short* WoT = WB + 768 * 64;
  unsigned short* A   = WB + wElems;

  k_prep<<<dim3(448), dim3(256), 0, stream>>>(Wq, Wk, Wv, Wo, WB, WoT);
  k_fattn<<<dim3(kBN * kH), dim3(1024), 0, stream>>>(x, WB, bq, bk, bv, A);
  k_proj<<<dim3(kBN * 4), dim3(512), 0, stream>>>(A, WoT, bo, out);
}

// Round 11
// 118.655 us; speedup vs baseline: 3.2532x; 1.0658x over previous
//
#include <hip/hip_runtime.h>

// Problem constants
constexpr int kT = 512;     // sequence length
constexpr int kF = 64;      // input features
constexpr int kC = 256;     // f_out
constexpr int kH = 4;       // heads
constexpr int kHD = 64;     // head dim
constexpr int kBN = 128;    // B*N independent problems

typedef __attribute__((ext_vector_type(4))) float f32x4;
typedef __attribute__((ext_vector_type(8))) short s16x8;
typedef __attribute__((ext_vector_type(4))) unsigned int u32x4;

__device__ inline unsigned short f2bf(float f) {
  unsigned int u = __float_as_uint(f);
  u += 0x7fff + ((u >> 16) & 1);  // round-to-nearest-even
  return (unsigned short)(u >> 16);
}

__device__ inline float max3f(float a, float b, float c) {
  return fmaxf(fmaxf(a, b), c);   // fuses to v_max3_f32
}

__device__ inline float exp2_hw(float x) {
  float r;
  asm("v_exp_f32 %0, %1" : "=v"(r) : "v"(x));
  return r;
}

// ---------------------------------------------------------------------------
// Kernel 0: weight precompute.
// WB  [768][64]  = [Wq;Wk;Wv]^T rows c, cols f   (bf16)
// WoT [256][256] = Wo^T rows co, cols c          (bf16)
// ---------------------------------------------------------------------------
__global__ __launch_bounds__(256) void k_prep(
    const float* __restrict__ Wq, const float* __restrict__ Wk,
    const float* __restrict__ Wv, const float* __restrict__ Wo,
    unsigned short* __restrict__ WB, unsigned short* __restrict__ WoT) {
  int i = blockIdx.x * 256 + threadIdx.x;
  const int total = 768 * 64 + 256 * 256;
  for (; i < total; i += gridDim.x * 256) {
    if (i < 768 * 64) {
      int c = i >> 6, f = i & 63;
      int arr = c >> 8, cc = c & 255;
      const float* W = (arr == 0) ? Wq : (arr == 1) ? Wk : Wv;
      WB[i] = f2bf(W[f * 256 + cc]);
    } else {
      int j = i - 768 * 64;
      int co = j >> 8, c = j & 255;
      WoT[j] = f2bf(Wo[c * 256 + co]);
    }
  }
}

// ---------------------------------------------------------------------------
// Kernel 1: FUSED QKV + flash attention per (bn, head). 1024 thr = 16 waves.
// Per 128-t chunk: stage x^T (bf16) -> all waves compute K (packed 8B
// [t][d] swizzled store) and V (operand-swapped mfma -> row=t layout ->
// single packed 8B kappa-store into [d][pos]); the 4 q-owning waves also
// compute Q and redistribute into B-frag layout via in-register shfl.
// FIX vs r10: shfl transports the SOURCE lane's register selection, so we
// shuffle BOTH d-half registers and select AFTER with the dest lane's sel.
// 2 barriers per chunk. Attention loop: r5-proven.
// ---------------------------------------------------------------------------
__global__ __launch_bounds__(1024, 4) void k_fattn(
    const float* __restrict__ x, const unsigned short* __restrict__ WB,
    const float* __restrict__ bq, const float* __restrict__ bk,
    const float* __restrict__ bv, unsigned short* __restrict__ Aw) {
  __shared__ __align__(16) unsigned char smem[149504];
  unsigned char* Kl = smem;                              // 64 KB  [512][128B] swz
  unsigned char* VtB = smem + 65536;                     // 64 KB  [64][1024B] swz
  unsigned short* xC = (unsigned short*)(smem + 131072); // 18 KB  [128][72] u16

  const int tid = threadIdx.x;
  const int lbn = blockIdx.x >> 2;
  const int h = blockIdx.x & 3;
  const int lane = tid & 63, wid = tid >> 6;
  const int lr = lane & 15, lg = lane >> 4;
  const int swz = (lr & 7) << 4;

  const float kQscale = 0.180336880111120426f;  // 0.125 * log2(e)
  const unsigned short* WBq = WB + (size_t)(h * 64) * 64;
  const unsigned short* WBk = WB + (size_t)(256 + h * 64) * 64;
  const unsigned short* WBv = WB + (size_t)(512 + h * 64) * 64;

  s16x8 qf[2][2];

  // ============ QKV build (2 barriers per chunk) ============
  for (int tch = 0; tch < 4; ++tch) {
    __syncthreads();  // prior-phase xC reads done before overwrite
    const float* xb = x + (size_t)lbn * kF * kT + tch * 128;
#pragma unroll
    for (int it = 0; it < 2; ++it) {
      int idx = tid + it * 1024;
      int f = idx >> 5, t4 = idx & 31;
      float4 v = *(const float4*)(xb + f * kT + t4 * 4);
      xC[(t4 * 4 + 0) * 72 + f] = f2bf(v.x);
      xC[(t4 * 4 + 1) * 72 + f] = f2bf(v.y);
      xC[(t4 * 4 + 2) * 72 + f] = f2bf(v.z);
      xC[(t4 * 4 + 3) * 72 + f] = f2bf(v.w);
    }
    __syncthreads();  // xC ready

    // K/V tiles: tau = wid*4 + j ; tau<32 -> K(ct=tau>>3,tt=tau&7), else V
#pragma unroll
    for (int j = 0; j < 4; ++j) {
      const int tau = wid * 4 + j;
      const int isV = tau >> 5;
      const int tl = tau & 31;
      const int ct = tl >> 3, tt = tl & 7;
      const unsigned short* Wsrc = isV ? WBv : WBk;
      s16x8 af0 = *(const s16x8*)(Wsrc + (ct * 16 + lr) * 64 + lg * 8);
      s16x8 af1 = *(const s16x8*)(Wsrc + (ct * 16 + lr) * 64 + 32 + lg * 8);
      s16x8 bf0 = *(const s16x8*)&xC[(tt * 16 + lr) * 72 + lg * 8];
      s16x8 bf1 = *(const s16x8*)&xC[(tt * 16 + lr) * 72 + 32 + lg * 8];
      if (!isV) {
        // K: row = c(d), col = t -> lane holds 4 consecutive d at one t
        f32x4 a = {0.f, 0.f, 0.f, 0.f};
        a = __builtin_amdgcn_mfma_f32_16x16x32_bf16(af0, bf0, a, 0, 0, 0);
        a = __builtin_amdgcn_mfma_f32_16x16x32_bf16(af1, bf1, a, 0, 0, 0);
        const int dbase = ct * 16 + lg * 4;
        const int t = tch * 128 + tt * 16 + lr;
        float v0 = a[0] + bk[h * 64 + dbase + 0];
        float v1 = a[1] + bk[h * 64 + dbase + 1];
        float v2 = a[2] + bk[h * 64 + dbase + 2];
        float v3 = a[3] + bk[h * 64 + dbase + 3];
        unsigned long long pk =
            (unsigned long long)f2bf(v0) |
            ((unsigned long long)f2bf(v1) << 16) |
            ((unsigned long long)f2bf(v2) << 32) |
            ((unsigned long long)f2bf(v3) << 48);
        *(unsigned long long*)(Kl + ((t * 128 + dbase * 2) ^ ((t & 7) << 4))) = pk;
      } else {
        // V swapped: row = t, col = d -> lane holds 4 consecutive t at one d
        f32x4 a = {0.f, 0.f, 0.f, 0.f};
        a = __builtin_amdgcn_mfma_f32_16x16x32_bf16(bf0, af0, a, 0, 0, 0);
        a = __builtin_amdgcn_mfma_f32_16x16x32_bf16(bf1, af1, a, 0, 0, 0);
        const int d = ct * 16 + lr;
        const float bias = bv[h * 64 + d];
        const int t0 = tch * 128 + tt * 16 + lg * 4;   // t0..t0+3, t0%4==0
        // kappa: pos = b32<<5 | hh<<3 | e<<2 | j2 for t = {b32,e,hh,j2}
        const int pos0 = ((t0 >> 5) << 5) | (((t0 >> 2) & 3) << 3) |
                         (((t0 >> 4) & 1) << 2);
        unsigned long long pk =
            (unsigned long long)f2bf(a[0] + bias) |
            ((unsigned long long)f2bf(a[1] + bias) << 16) |
            ((unsigned long long)f2bf(a[2] + bias) << 32) |
            ((unsigned long long)f2bf(a[3] + bias) << 48);
        *(unsigned long long*)(VtB + ((d * 1024 + pos0 * 2) ^ ((d & 7) << 4))) = pk;
      }
    }

    // Q: the 4 waves owning this chunk's q-rows; register-only redistribute
    if ((wid >> 2) == tch) {
      f32x4 qa[2][4];
#pragma unroll
      for (int qt = 0; qt < 2; ++qt) {
        const int ttq = (wid & 3) * 2 + qt;
#pragma unroll
        for (int ct = 0; ct < 4; ++ct) {
          s16x8 af0 = *(const s16x8*)(WBq + (ct * 16 + lr) * 64 + lg * 8);
          s16x8 af1 = *(const s16x8*)(WBq + (ct * 16 + lr) * 64 + 32 + lg * 8);
          s16x8 bf0 = *(const s16x8*)&xC[(ttq * 16 + lr) * 72 + lg * 8];
          s16x8 bf1 = *(const s16x8*)&xC[(ttq * 16 + lr) * 72 + 32 + lg * 8];
          f32x4 a = {0.f, 0.f, 0.f, 0.f};
          a = __builtin_amdgcn_mfma_f32_16x16x32_bf16(af0, bf0, a, 0, 0, 0);
          a = __builtin_amdgcn_mfma_f32_16x16x32_bf16(af1, bf1, a, 0, 0, 0);
          const int dbase = ct * 16 + lg * 4;
#pragma unroll
          for (int r = 0; r < 4; ++r)
            a[r] = (a[r] + bq[h * 64 + dbase + r]) * kQscale;
          qa[qt][ct] = a;
        }
      }
      // qf[qt][half][j] = Q[q=qbase+qt*16+lr][d=half*32+lg*8+j]
      //   = qa[qt][half*2 + (lg>>1)][j&3] taken from lane ((lg&1)*2+(j>>2))*16+lr
      // shfl returns the SOURCE lane's operand -> shuffle both ct candidates,
      // select after with the DEST lane's sel.
      const int sel = lg >> 1;
#pragma unroll
      for (int qt = 0; qt < 2; ++qt)
#pragma unroll
        for (int half = 0; half < 2; ++half) {
          unsigned int w[4];
#pragma unroll
          for (int i2 = 0; i2 < 4; ++i2) {
            const int r0 = (i2 & 1) * 2;          // j&3 for j=2*i2
            const int lgp = (lg & 1) * 2 + (i2 >> 1);
            const int src = lgp * 16 + lr;
            float loA = __shfl(qa[qt][half * 2 + 0][r0], src);
            float hiA = __shfl(qa[qt][half * 2 + 1][r0], src);
            float loB = __shfl(qa[qt][half * 2 + 0][r0 + 1], src);
            float hiB = __shfl(qa[qt][half * 2 + 1][r0 + 1], src);
            float eA = sel ? hiA : loA;
            float eB = sel ? hiB : loB;
            asm("v_cvt_pk_bf16_f32 %0, %1, %2"
                : "=v"(w[i2]) : "v"(eA), "v"(eB));
          }
          qf[qt][half] =
              __builtin_bit_cast(s16x8, (u32x4){w[0], w[1], w[2], w[3]});
        }
    }
  }
  __syncthreads();  // Kl/VtB complete

  // ============ attention (r5-proven) ============
  unsigned short* Ab = Aw + (size_t)lbn * kT * kC + h * kHD;
  const int qbase = wid * 32;

  f32x4 o0[4] = {{0,0,0,0},{0,0,0,0},{0,0,0,0},{0,0,0,0}};
  f32x4 o1[4] = {{0,0,0,0},{0,0,0,0},{0,0,0,0},{0,0,0,0}};
  float m0 = -3e38f, m1 = -3e38f, l0 = 0.f, l1 = 0.f;

  const int koff = (lg * 16) ^ swz;
  const unsigned char* kp0 = Kl + lr * 128 + koff;
  const unsigned char* kp1 = Kl + lr * 128 + (koff ^ 64);
  const unsigned char* vp0 = VtB + lr * 1024 + ((lg * 16) ^ swz);
  const unsigned char* vp1 = VtB + lr * 1024 + (((lg * 16) ^ 64) ^ swz);

  unsigned int w0[8], w1[8];

#define SOFTMAX_QT(sa, m, l, o, w)                                            \
  {                                                                           \
    float g0 = max3f(sa[0][0], sa[0][1], sa[0][2]);                           \
    float g1 = max3f(sa[0][3], sa[1][0], sa[1][1]);                           \
    float g2 = max3f(sa[1][2], sa[1][3], sa[2][0]);                           \
    float g3 = max3f(sa[2][1], sa[2][2], sa[2][3]);                           \
    float g4 = max3f(sa[3][0], sa[3][1], sa[3][2]);                           \
    float tm = fmaxf(max3f(g0, g1, g2), max3f(g3, g4, sa[3][3]));             \
    if (__any(tm > m + 8.0f)) {                                               \
      tm = fmaxf(tm, __shfl_xor(tm, 16));                                     \
      tm = fmaxf(tm, __shfl_xor(tm, 32));                                     \
      float mn = fmaxf(m, tm);                                                \
      float al = exp2_hw(m - mn);                                             \
      m = mn;                                                                 \
      l *= al;                                                                \
      float aq0 = __shfl(al, (lane & 48) | (lg * 4 + 0));                     \
      float aq1 = __shfl(al, (lane & 48) | (lg * 4 + 1));                     \
      float aq2 = __shfl(al, (lane & 48) | (lg * 4 + 2));                     \
      float aq3 = __shfl(al, (lane & 48) | (lg * 4 + 3));                     \
      _Pragma("unroll")                                                       \
      for (int dt = 0; dt < 4; ++dt) {                                        \
        o[dt][0] *= aq0; o[dt][1] *= aq1;                                     \
        o[dt][2] *= aq2; o[dt][3] *= aq3;                                     \
      }                                                                       \
    }                                                                         \
    _Pragma("unroll")                                                         \
    for (int s = 0; s < 4; ++s) {                                             \
      float e0 = exp2_hw(sa[s][0] - m);                                       \
      float e1 = exp2_hw(sa[s][1] - m);                                       \
      float e2 = exp2_hw(sa[s][2] - m);                                       \
      float e3 = exp2_hw(sa[s][3] - m);                                       \
      l += (e0 + e1) + (e2 + e3);                                             \
      asm("v_cvt_pk_bf16_f32 %0, %1, %2" : "=v"(w[2*s]) : "v"(e0), "v"(e1));  \
      asm("v_cvt_pk_bf16_f32 %0, %1, %2" : "=v"(w[2*s+1]) : "v"(e2), "v"(e3));\
    }                                                                         \
  }

  for (int kc = 0; kc < 8; ++kc) {
    f32x4 sa0[4], sa1[4];
#pragma unroll
    for (int s = 0; s < 4; ++s) {
      s16x8 kf0 = *(const s16x8*)(kp0 + s * 2048);
      s16x8 kf1 = *(const s16x8*)(kp1 + s * 2048);
      f32x4 z0 = {0.f, 0.f, 0.f, 0.f};
      z0 = __builtin_amdgcn_mfma_f32_16x16x32_bf16(kf0, qf[0][0], z0, 0, 0, 0);
      z0 = __builtin_amdgcn_mfma_f32_16x16x32_bf16(kf1, qf[0][1], z0, 0, 0, 0);
      sa0[s] = z0;
      f32x4 z1 = {0.f, 0.f, 0.f, 0.f};
      z1 = __builtin_amdgcn_mfma_f32_16x16x32_bf16(kf0, qf[1][0], z1, 0, 0, 0);
      z1 = __builtin_amdgcn_mfma_f32_16x16x32_bf16(kf1, qf[1][1], z1, 0, 0, 0);
      sa1[s] = z1;
    }
    kp0 += 8192;
    kp1 += 8192;

    SOFTMAX_QT(sa0, m0, l0, o0, w0)
    SOFTMAX_QT(sa1, m1, l1, o1, w1)

    s16x8 pa00 = __builtin_bit_cast(s16x8, (u32x4){w0[0], w0[1], w0[2], w0[3]});
    s16x8 pa01 = __builtin_bit_cast(s16x8, (u32x4){w0[4], w0[5], w0[6], w0[7]});
    s16x8 pa10 = __builtin_bit_cast(s16x8, (u32x4){w1[0], w1[1], w1[2], w1[3]});
    s16x8 pa11 = __builtin_bit_cast(s16x8, (u32x4){w1[4], w1[5], w1[6], w1[7]});

#pragma unroll
    for (int dt = 0; dt < 4; ++dt) {
      s16x8 vb = *(const s16x8*)(vp0 + dt * 16384);
      o0[dt] = __builtin_amdgcn_mfma_f32_16x16x32_bf16(pa00, vb, o0[dt], 0, 0, 0);
      o1[dt] = __builtin_amdgcn_mfma_f32_16x16x32_bf16(pa10, vb, o1[dt], 0, 0, 0);
    }
#pragma unroll
    for (int dt = 0; dt < 4; ++dt) {
      s16x8 vb = *(const s16x8*)(vp1 + dt * 16384);
      o0[dt] = __builtin_amdgcn_mfma_f32_16x16x32_bf16(pa01, vb, o0[dt], 0, 0, 0);
      o1[dt] = __builtin_amdgcn_mfma_f32_16x16x32_bf16(pa11, vb, o1[dt], 0, 0, 0);
    }
    vp0 += 128;
    vp1 += 128;
  }
#undef SOFTMAX_QT

  // epilogue: cross-lane l sum, normalize, write
#pragma unroll
  for (int qt = 0; qt < 2; ++qt) {
    float l = (qt == 0) ? l0 : l1;
    f32x4* o = (qt == 0) ? o0 : o1;
    float l2 = l + __shfl_xor(l, 16);
    float lr4 = l2 + __shfl_xor(l2, 32);
    float li0 = 1.0f / __shfl(lr4, (lane & 48) | (lg * 4 + 0));
    float li1 = 1.0f / __shfl(lr4, (lane & 48) | (lg * 4 + 1));
    float li2 = 1.0f / __shfl(lr4, (lane & 48) | (lg * 4 + 2));
    float li3 = 1.0f / __shfl(lr4, (lane & 48) | (lg * 4 + 3));
    const int qb = qbase + qt * 16;
#pragma unroll
    for (int r = 0; r < 4; ++r) {
      float li = (r == 0) ? li0 : (r == 1) ? li1 : (r == 2) ? li2 : li3;
      unsigned short* orow = Ab + (size_t)(qb + lg * 4 + r) * kC;
#pragma unroll
      for (int dt = 0; dt < 4; ++dt)
        orow[dt * 16 + lr] = f2bf(o[dt][r] * li);
    }
  }
}

// ---------------------------------------------------------------------------
// Kernel 3: output projection + bias + transpose. Block = (bn, 128-t chunk),
// 512 thr = 8 waves (2 t-halves x 4 co-quads). A staged ONCE in swizzled LDS.
// out[bn][co][t] fp32.
// ---------------------------------------------------------------------------
__global__ __launch_bounds__(512) void k_proj(
    const unsigned short* __restrict__ Aw, const unsigned short* __restrict__ WoT,
    const float* __restrict__ bo, float* __restrict__ out) {
  __shared__ __align__(16) unsigned char Al[128 * 512];  // [t][c] swizzled, 64KB

  const int tid = threadIdx.x;
  const int lbn = blockIdx.x >> 2;
  const int tch = blockIdx.x & 3;
  const int t0 = tch * 128;

  const uint4* Asrc = (const uint4*)(Aw + ((size_t)lbn * kT + t0) * kC);
#pragma unroll
  for (int i = 0; i < 8; ++i) {
    int idx = tid + i * 512;
    int trow = idx >> 5, cc = idx & 31;
    *(uint4*)(Al + ((trow * 512 + cc * 16) ^ ((trow & 7) << 4))) = Asrc[idx];
  }
  __syncthreads();

  const int lane = tid & 63, wid = tid >> 6;
  const int lr = lane & 15, lg = lane >> 4;
  const int swz = (lr & 7) << 4;
  const int tb = (wid >> 2) * 64;
  const int cob = (wid & 3) * 64;

  float* ob = out + (size_t)lbn * kC * kT;

  for (int ci = 0; ci < 4; ++ci) {
    const int co0 = cob + ci * 16;
    s16x8 af[8];
#pragma unroll
    for (int kc = 0; kc < 8; ++kc)
      af[kc] = *(const s16x8*)(WoT + (size_t)(co0 + lr) * 256 + kc * 32 + lg * 8);
    float b4[4];
#pragma unroll
    for (int r = 0; r < 4; ++r) b4[r] = bo[co0 + lg * 4 + r];

#pragma unroll
    for (int tj = 0; tj < 4; ++tj) {
      const unsigned char* ap = Al + (tb + tj * 16 + lr) * 512;
      f32x4 acc = {0.f, 0.f, 0.f, 0.f};
#pragma unroll
      for (int kc = 0; kc < 8; ++kc) {
        s16x8 bfr = *(const s16x8*)(ap + ((kc * 64 + lg * 16) ^ swz));
        acc = __builtin_amdgcn_mfma_f32_16x16x32_bf16(af[kc], bfr, acc, 0, 0, 0);
      }
      int t = t0 + tb + tj * 16 + lr;
#pragma unroll
      for (int r = 0; r < 4; ++r)
        ob[(size_t)(co0 + lg * 4 + r) * kT + t] = acc[r] + b4[r];
    }
  }
}

// ---------------------------------------------------------------------------
extern "C" void kernel_launch(void* const* d_in, const int* in_sizes, int n_in,
                              void* d_out, int out_size, void* d_ws, size_t ws_size,
                              hipStream_t stream) {
  const float* x  = (const float*)d_in[0];
  const float* Wq = (const float*)d_in[1];
  const float* bq = (const float*)d_in[2];
  const float* Wk = (const float*)d_in[3];
  const float* bk = (const float*)d_in[4];
  const float* Wv = (const float*)d_in[5];
  const float* bv = (const float*)d_in[6];
  const float* Wo = (const float*)d_in[7];
  const float* bo = (const float*)d_in[8];
  float* out = (float*)d_out;

  // ws layout: WB bf16 [768*64] | WoT bf16 [256*256] | A bf16 [128*512*256]
  const size_t wElems = 768 * 64 + 256 * 256;             // 229376 B
  const size_t aBytes = (size_t)kBN * kT * kC * 2;        // 32 MB
  if (ws_size < wElems * 2 + aBytes) return;

  unsigned short* WB  = (unsigned short*)d_ws;
  unsigned short* WoT = WB + 768 * 64;
  unsigned short* A   = WB + wElems;

  k_prep<<<dim3(448), dim3(256), 0, stream>>>(Wq, Wk, Wv, Wo, WB, WoT);
  k_fattn<<<dim3(kBN * kH), dim3(1024), 0, stream>>>(x, WB, bq, bk, bv, A);
  k_proj<<<dim3(kBN * 4), dim3(512), 0, stream>>>(A, WoT, bo, out);
}